// Round 10
// baseline (216.028 us; speedup 1.0000x reference)
//
#include <hip/hip_runtime.h>

// ---------------------------------------------------------------------------
// 2-layer GCN on MI355X — round 10 (= round 9 fixed): fill ∥ mm1 fused at FULL
// fill parallelism, nontemporal streaming via ext_vector types (HIP int4/uint4
// are classes -> rejected by __builtin_nontemporal_*), inline dinv, fused prep.
//   g = X W (unscaled bf16); out[i] = act( dinv[i]*(dinv[i]*g[i] + Σ dinv[s]*g[s]) + b )
// ---------------------------------------------------------------------------

#define MD 48        // ELL width; deg ~ Poisson(10), P(deg>=48) ~ 1e-18
#define FILLB 8192   // fill blocks in fused kernel (= r8 standalone parallelism)

typedef __attribute__((ext_vector_type(8))) short bf16x8;   // 8 bf16 = 4 VGPRs
typedef __attribute__((ext_vector_type(4))) float f32x4;
typedef __attribute__((ext_vector_type(4))) int   i32x4;
typedef __attribute__((ext_vector_type(4))) unsigned u32x4;

__device__ inline float bf2f(unsigned short v) {
    unsigned u = (unsigned)v << 16;
    return __builtin_bit_cast(float, u);
}
__device__ inline unsigned short f2bf(float f) {  // round-to-nearest-even
    unsigned u = __builtin_bit_cast(unsigned, f);
    unsigned r = (u + 0x7FFFu + ((u >> 16) & 1u)) >> 16;
    return (unsigned short)r;
}

// --- fused prep: zero cnt | convert W1 | convert W2 ------------------------
__device__ inline void convW_one(const float* __restrict__ W, short* __restrict__ Wth,
                                 short* __restrict__ Wtl, int K, int k, int f) {
    float v = W[k * 64 + f];
    unsigned b = __builtin_bit_cast(unsigned, v);
    unsigned hb = b & 0xFFFF0000u;
    float d = v - __builtin_bit_cast(float, hb);
    unsigned lb = __builtin_bit_cast(unsigned, d);
    Wth[f * K + k] = (short)(hb >> 16);
    Wtl[f * K + k] = (short)(lb >> 16);
}

__global__ __launch_bounds__(256) void k_prep(int* __restrict__ cnt, int n, int nbz,
                                              const float* __restrict__ W1,
                                              short* __restrict__ W1th, short* __restrict__ W1tl,
                                              const float* __restrict__ W2,
                                              short* __restrict__ W2th, short* __restrict__ W2tl) {
    const int b = blockIdx.x;
    if (b < nbz) {
        int i = b * 256 + threadIdx.x;
        if (i < n) cnt[i] = 0;
    } else if (b < nbz + 128) {
        if (threadIdx.x < 64) convW_one(W1, W1th, W1tl, 128, b - nbz, threadIdx.x);
    } else {
        if (threadIdx.x < 64) convW_one(W2, W2th, W2tl, 64, b - nbz - 128, threadIdx.x);
    }
}

// --- mm1 body: G[row,64] = bf16( X[row,0:K] @ W ), f32 A hi/lo 3-term MFMA --
template <int K>
__device__ inline void mm_f32A_body(int bid, const float* __restrict__ X,
                                    const short* __restrict__ Wth,
                                    const short* __restrict__ Wtl,
                                    unsigned short* __restrict__ G, int n) {
    const int lane = threadIdx.x & 63;
    const int w = threadIdx.x >> 6;
    const int r0 = lane & 15;
    const int kq = lane >> 4;
    const int arow = bid * 64 + w * 16 + r0;
    const float* xrow = X + (size_t)(arow < n ? arow : n - 1) * K;

    f32x4 acc[4] = {};
#pragma unroll
    for (int kc = 0; kc < K / 32; ++kc) {
        const int ks = kc * 32 + kq * 8;
        float xv[8];
        *(f32x4*)&xv[0] = __builtin_nontemporal_load((const f32x4*)&xrow[ks]);
        *(f32x4*)&xv[4] = __builtin_nontemporal_load((const f32x4*)&xrow[ks + 4]);
        bf16x8 ah, al;
#pragma unroll
        for (int j = 0; j < 8; ++j) {
            unsigned b = __builtin_bit_cast(unsigned, xv[j]);
            unsigned hb = b & 0xFFFF0000u;
            float d = xv[j] - __builtin_bit_cast(float, hb);
            unsigned lb = __builtin_bit_cast(unsigned, d);
            ah[j] = (short)(hb >> 16);
            al[j] = (short)(lb >> 16);
        }
#pragma unroll
        for (int c = 0; c < 4; ++c) {
            bf16x8 bh = *(const bf16x8*)&Wth[(c * 16 + r0) * K + ks];
            bf16x8 bl = *(const bf16x8*)&Wtl[(c * 16 + r0) * K + ks];
            acc[c] = __builtin_amdgcn_mfma_f32_16x16x32_bf16(ah, bh, acc[c], 0, 0, 0);
            acc[c] = __builtin_amdgcn_mfma_f32_16x16x32_bf16(ah, bl, acc[c], 0, 0, 0);
            acc[c] = __builtin_amdgcn_mfma_f32_16x16x32_bf16(al, bh, acc[c], 0, 0, 0);
        }
    }
    const int orow = bid * 64 + w * 16 + kq * 4;  // C/D: col=lane&15, row=(lane>>4)*4+reg
#pragma unroll
    for (int rg = 0; rg < 4; ++rg) {
        int gr = orow + rg;
        if (gr < n) {
#pragma unroll
            for (int c = 0; c < 4; ++c)
                G[(size_t)gr * 64 + c * 16 + r0] = f2bf(acc[c][rg]);
        }
    }
}

// --- fused: blocks [0,FILLB) = XCD-partitioned ELL fill; rest = mm1 --------
template <int K>
__global__ __launch_bounds__(256) void k_fill_mm1(const int* __restrict__ src,
                                                  const int* __restrict__ dst, int E,
                                                  int* __restrict__ cnt,
                                                  int* __restrict__ col_ell, int npx,
                                                  const float* __restrict__ X,
                                                  const short* __restrict__ Wth,
                                                  const short* __restrict__ Wtl,
                                                  unsigned short* __restrict__ G, int n) {
    if (blockIdx.x < FILLB) {
        const int myxcd = blockIdx.x & 7;
        const int lo = myxcd * npx;
        const int hi = lo + npx;
        const int vb = blockIdx.x >> 3;
        const int nvb = FILLB >> 3;
        const int tid = vb * 256 + threadIdx.x;
        const int nthr = nvb * 256;
        for (int base = tid * 4; base < E; base += nthr * 4) {  // E % 4 == 0
            i32x4 d4 = __builtin_nontemporal_load((const i32x4*)&dst[base]);
#pragma unroll
            for (int k = 0; k < 4; ++k) {
                int d = d4[k];
                if (d >= lo && d < hi) {
                    int p = atomicAdd(&cnt[d], 1);
                    if (p < MD)
                        col_ell[(size_t)d * MD + p] = __builtin_nontemporal_load(&src[base + k]);
                }
            }
        }
    } else {
        mm_f32A_body<K>(blockIdx.x - FILLB, X, Wth, Wtl, G, n);
    }
}

// --- G[n,64] = bf16( A[n,64] @ W[64,64] ), A = bf16 exact, 2-term MFMA -----
__global__ __launch_bounds__(256) void k_mm_bf16A(const unsigned short* __restrict__ A,
                                                  const short* __restrict__ Wth,
                                                  const short* __restrict__ Wtl,
                                                  unsigned short* __restrict__ G, int n) {
    constexpr int K = 64;
    const int lane = threadIdx.x & 63;
    const int w = threadIdx.x >> 6;
    const int r0 = lane & 15;
    const int kq = lane >> 4;
    const int arow = blockIdx.x * 64 + w * 16 + r0;
    const unsigned short* ar = A + (size_t)(arow < n ? arow : n - 1) * K;

    f32x4 acc[4] = {};
#pragma unroll
    for (int kc = 0; kc < K / 32; ++kc) {
        const int ks = kc * 32 + kq * 8;
        bf16x8 a = __builtin_nontemporal_load((const bf16x8*)&ar[ks]);
#pragma unroll
        for (int c = 0; c < 4; ++c) {
            bf16x8 bh = *(const bf16x8*)&Wth[(c * 16 + r0) * K + ks];
            bf16x8 bl = *(const bf16x8*)&Wtl[(c * 16 + r0) * K + ks];
            acc[c] = __builtin_amdgcn_mfma_f32_16x16x32_bf16(a, bh, acc[c], 0, 0, 0);
            acc[c] = __builtin_amdgcn_mfma_f32_16x16x32_bf16(a, bl, acc[c], 0, 0, 0);
        }
    }
    const int orow = blockIdx.x * 64 + w * 16 + kq * 4;
#pragma unroll
    for (int rg = 0; rg < 4; ++rg) {
        int gr = orow + rg;
        if (gr < n) {
#pragma unroll
            for (int c = 0; c < 4; ++c)
                G[(size_t)gr * 64 + c * 16 + r0] = f2bf(acc[c][rg]);
        }
    }
}

// --- ELL gather, 8 edges in flight; dinv = rsqrt(cnt+1) computed inline ----
// out[i] = act( dinv[i]*( dinv[i]*g[i] + Σ_p dinv[s_p]*g[s_p] ) + b )
template <bool RELU, bool OUTBF>
__global__ __launch_bounds__(256) void k_gather8(const unsigned short* __restrict__ g,
                                                 const int* __restrict__ cntArr,
                                                 const int* __restrict__ col_ell,
                                                 const float* __restrict__ bias,
                                                 void* __restrict__ dest, int n) {
    const int node = blockIdx.x * 4 + (threadIdx.x >> 6);
    if (node >= n) return;
    const int lane = threadIdx.x & 63;
    const int grp = lane >> 3;   // 0..7 : edge sub-group
    const int fl = lane & 7;     // feature octet [fl*8, fl*8+8)
    const int cn = cntArr[node];
    const int lc = min(cn, MD);
    const float dn = rsqrtf((float)(cn + 1));
    const int myidx = __builtin_nontemporal_load(&col_ell[(size_t)node * MD + lane]);
    const int vidx = (lane < lc) ? myidx : node;          // guard stale idx
    const float mydv = rsqrtf((float)(cntArr[vidx] + 1));

    float acc[8] = {};
    if (grp == 0) {  // self loop: dinv[node]*g[node]
        u32x4 u = *(const u32x4*)&g[(size_t)node * 64 + fl * 8];
        acc[0] = dn * bf2f((unsigned short)(u[0] & 0xFFFF));
        acc[1] = dn * bf2f((unsigned short)(u[0] >> 16));
        acc[2] = dn * bf2f((unsigned short)(u[1] & 0xFFFF));
        acc[3] = dn * bf2f((unsigned short)(u[1] >> 16));
        acc[4] = dn * bf2f((unsigned short)(u[2] & 0xFFFF));
        acc[5] = dn * bf2f((unsigned short)(u[2] >> 16));
        acc[6] = dn * bf2f((unsigned short)(u[3] & 0xFFFF));
        acc[7] = dn * bf2f((unsigned short)(u[3] >> 16));
    }
    for (int j8 = 0; j8 < lc; j8 += 8) {
        int j = j8 + grp;
        int s = __shfl(myidx, j);
        float ds = __shfl(mydv, j);
        if (j < lc) {
            u32x4 u = *(const u32x4*)&g[(size_t)s * 64 + fl * 8];
            acc[0] = fmaf(ds, bf2f((unsigned short)(u[0] & 0xFFFF)), acc[0]);
            acc[1] = fmaf(ds, bf2f((unsigned short)(u[0] >> 16)),    acc[1]);
            acc[2] = fmaf(ds, bf2f((unsigned short)(u[1] & 0xFFFF)), acc[2]);
            acc[3] = fmaf(ds, bf2f((unsigned short)(u[1] >> 16)),    acc[3]);
            acc[4] = fmaf(ds, bf2f((unsigned short)(u[2] & 0xFFFF)), acc[4]);
            acc[5] = fmaf(ds, bf2f((unsigned short)(u[2] >> 16)),    acc[5]);
            acc[6] = fmaf(ds, bf2f((unsigned short)(u[3] & 0xFFFF)), acc[6]);
            acc[7] = fmaf(ds, bf2f((unsigned short)(u[3] >> 16)),    acc[7]);
        }
    }
#pragma unroll
    for (int k = 0; k < 8; ++k) {
        acc[k] += __shfl_xor(acc[k], 8);
        acc[k] += __shfl_xor(acc[k], 16);
        acc[k] += __shfl_xor(acc[k], 32);
    }
    if (grp == 0) {
        float v[8];
        const float* bv = &bias[fl * 8];
#pragma unroll
        for (int k = 0; k < 8; ++k) {
            v[k] = fmaf(acc[k], dn, bv[k]);
            if (RELU) v[k] = fmaxf(v[k], 0.f);
        }
        if (OUTBF) {
            u32x4 o;
            o[0] = (unsigned)f2bf(v[0]) | ((unsigned)f2bf(v[1]) << 16);
            o[1] = (unsigned)f2bf(v[2]) | ((unsigned)f2bf(v[3]) << 16);
            o[2] = (unsigned)f2bf(v[4]) | ((unsigned)f2bf(v[5]) << 16);
            o[3] = (unsigned)f2bf(v[6]) | ((unsigned)f2bf(v[7]) << 16);
            __builtin_nontemporal_store(o, (u32x4*)&((unsigned short*)dest)[(size_t)node * 64 + fl * 8]);
        } else {
            float* dp = &((float*)dest)[(size_t)node * 64 + fl * 8];
            __builtin_nontemporal_store(*(const f32x4*)&v[0], (f32x4*)&dp[0]);
            __builtin_nontemporal_store(*(const f32x4*)&v[4], (f32x4*)&dp[4]);
        }
    }
}

extern "C" void kernel_launch(void* const* d_in, const int* in_sizes, int n_in,
                              void* d_out, int out_size, void* d_ws, size_t ws_size,
                              hipStream_t stream) {
    const float* x  = (const float*)d_in[0];
    const int*   ei = (const int*)d_in[1];
    const float* W1 = (const float*)d_in[2];
    const float* b1 = (const float*)d_in[3];
    const float* W2 = (const float*)d_in[4];
    const float* b2 = (const float*)d_in[5];

    const int N = in_sizes[0] / 128;   // 100000
    const int E = in_sizes[1] / 2;     // 1000000
    const int* src = ei;
    const int* dst = ei + E;
    float* out = (float*)d_out;

    // ws layout (64B-aligned slices)
    char* ws = (char*)d_ws;
    size_t off = 0;
    auto alloc = [&](size_t bytes) {
        void* p = ws + off;
        off += (bytes + 63) & ~(size_t)63;
        return p;
    };
    unsigned short* a1   = (unsigned short*)alloc((size_t)N * 64 * 2);  // bf16 act
    unsigned short* gbuf = (unsigned short*)alloc((size_t)N * 64 * 2);  // bf16 g
    int*   cnt     = (int*)alloc((size_t)N * 4);
    int*   col_ell = (int*)alloc(((size_t)N * MD + 64) * 4);  // +64 pad (64-lane row read)
    short* W1th    = (short*)alloc((size_t)64 * 128 * 2);
    short* W1tl    = (short*)alloc((size_t)64 * 128 * 2);
    short* W2th    = (short*)alloc((size_t)64 * 64 * 2);
    short* W2tl    = (short*)alloc((size_t)64 * 64 * 2);

    const int NBZ   = (N + 255) / 256;
    const int NB_MM = (N + 63) / 64;
    const int NB_G  = (N + 3) / 4;
    const int npx   = (N + 7) / 8;     // nodes per XCD partition

    // prep: zero cnt + convert both weights (one dispatch)
    k_prep<<<NBZ + 192, 256, 0, stream>>>(cnt, N, NBZ, W1, W1th, W1tl, W2, W2th, W2tl);

    // fill (XCD-partitioned, full parallelism) ∥ mm1 — independent work
    k_fill_mm1<128><<<FILLB + NB_MM, 256, 0, stream>>>(src, dst, E, cnt, col_ell, npx,
                                                       x, W1th, W1tl, gbuf, N);

    // ---- layer 1 aggregate ----
    k_gather8<true, true><<<NB_G, 256, 0, stream>>>(gbuf, cnt, col_ell, b1, a1, N);

    // ---- layer 2 ----
    k_mm_bf16A<<<NB_MM, 256, 0, stream>>>(a1, W2th, W2tl, gbuf, N);
    k_gather8<false, false><<<NB_G, 256, 0, stream>>>(gbuf, cnt, col_ell, b2, out, N);
}

// Round 11
// 187.106 us; speedup vs baseline: 1.1546x; 1.1546x over previous
//
#include <hip/hip_runtime.h>

// ---------------------------------------------------------------------------
// 2-layer GCN on MI355X — round 11: r8 structure restored (fusion abandoned:
// 2x failures; NT on multi-touch data doubled HBM fetch). Deltas vs r8:
//   * g pre-scaled by dinv in mm epilogues (dinv = rsqrt(cnt+1) inline)
//     -> gather loses 1M random per-slot dinv loads + one shfl
//   * NT only on single-touch streams (x, a1-in-mm2, final out store)
//   * fused prep (zero cnt + convW1 + convW2) in one dispatch
//   g = (X W)*dinv (bf16); out[i] = act( dinv[i]*(g[i] + Σ_s g[s]) + b )
// ---------------------------------------------------------------------------

#define MD 48        // ELL width; deg ~ Poisson(10), P(deg>=48) ~ 1e-18

typedef __attribute__((ext_vector_type(8))) short bf16x8;   // 8 bf16 = 4 VGPRs
typedef __attribute__((ext_vector_type(4))) float f32x4;
typedef __attribute__((ext_vector_type(4))) int   i32x4;
typedef __attribute__((ext_vector_type(4))) unsigned u32x4;

__device__ inline float bf2f(unsigned short v) {
    unsigned u = (unsigned)v << 16;
    return __builtin_bit_cast(float, u);
}
__device__ inline unsigned short f2bf(float f) {  // round-to-nearest-even
    unsigned u = __builtin_bit_cast(unsigned, f);
    unsigned r = (u + 0x7FFFu + ((u >> 16) & 1u)) >> 16;
    return (unsigned short)r;
}

// --- fused prep: zero cnt | convert W1 | convert W2 ------------------------
__device__ inline void convW_one(const float* __restrict__ W, short* __restrict__ Wth,
                                 short* __restrict__ Wtl, int K, int k, int f) {
    float v = W[k * 64 + f];
    unsigned b = __builtin_bit_cast(unsigned, v);
    unsigned hb = b & 0xFFFF0000u;
    float d = v - __builtin_bit_cast(float, hb);
    unsigned lb = __builtin_bit_cast(unsigned, d);
    Wth[f * K + k] = (short)(hb >> 16);
    Wtl[f * K + k] = (short)(lb >> 16);
}

__global__ __launch_bounds__(256) void k_prep(int* __restrict__ cnt, int n, int nbz,
                                              const float* __restrict__ W1,
                                              short* __restrict__ W1th, short* __restrict__ W1tl,
                                              const float* __restrict__ W2,
                                              short* __restrict__ W2th, short* __restrict__ W2tl) {
    const int b = blockIdx.x;
    if (b < nbz) {
        int i = b * 256 + threadIdx.x;
        if (i < n) cnt[i] = 0;
    } else if (b < nbz + 128) {
        if (threadIdx.x < 64) convW_one(W1, W1th, W1tl, 128, b - nbz, threadIdx.x);
    } else {
        if (threadIdx.x < 64) convW_one(W2, W2th, W2tl, 64, b - nbz - 128, threadIdx.x);
    }
}

// --- XCD-partitioned ELL fill (r8 verbatim — NO nontemporal) ---------------
__global__ __launch_bounds__(256) void k_fill_xcd(const int* __restrict__ src,
                                                  const int* __restrict__ dst, int E,
                                                  int* __restrict__ cnt,
                                                  int* __restrict__ col_ell, int npx) {
    const int myxcd = blockIdx.x & 7;
    const int lo = myxcd * npx;
    const int hi = lo + npx;
    const int vb = blockIdx.x >> 3;
    const int nvb = gridDim.x >> 3;
    const int tid = vb * 256 + threadIdx.x;
    const int nthr = nvb * 256;
    for (int base = tid * 4; base < E; base += nthr * 4) {  // E % 4 == 0
        i32x4 d4 = *(const i32x4*)&dst[base];
#pragma unroll
        for (int k = 0; k < 4; ++k) {
            int d = d4[k];
            if (d >= lo && d < hi) {
                int p = atomicAdd(&cnt[d], 1);
                if (p < MD) col_ell[(size_t)d * MD + p] = src[base + k];
            }
        }
    }
}

// --- G[n,64] = bf16( (X[n,K] @ W[K,64]) * rsqrt(cnt+1) ), A = f32 hi/lo ----
template <int K>
__global__ __launch_bounds__(256) void k_mm_f32A(const float* __restrict__ X,
                                                 const short* __restrict__ Wth,
                                                 const short* __restrict__ Wtl,
                                                 const int* __restrict__ cnt,
                                                 unsigned short* __restrict__ G, int n) {
    const int lane = threadIdx.x & 63;
    const int w = threadIdx.x >> 6;
    const int r0 = lane & 15;
    const int kq = lane >> 4;
    const int arow = blockIdx.x * 64 + w * 16 + r0;
    const float* xrow = X + (size_t)(arow < n ? arow : n - 1) * K;

    f32x4 acc[4] = {};
#pragma unroll
    for (int kc = 0; kc < K / 32; ++kc) {
        const int ks = kc * 32 + kq * 8;
        float xv[8];
        *(f32x4*)&xv[0] = __builtin_nontemporal_load((const f32x4*)&xrow[ks]);
        *(f32x4*)&xv[4] = __builtin_nontemporal_load((const f32x4*)&xrow[ks + 4]);
        bf16x8 ah, al;
#pragma unroll
        for (int j = 0; j < 8; ++j) {
            unsigned b = __builtin_bit_cast(unsigned, xv[j]);
            unsigned hb = b & 0xFFFF0000u;
            float d = xv[j] - __builtin_bit_cast(float, hb);
            unsigned lb = __builtin_bit_cast(unsigned, d);
            ah[j] = (short)(hb >> 16);
            al[j] = (short)(lb >> 16);
        }
#pragma unroll
        for (int c = 0; c < 4; ++c) {
            bf16x8 bh = *(const bf16x8*)&Wth[(c * 16 + r0) * K + ks];
            bf16x8 bl = *(const bf16x8*)&Wtl[(c * 16 + r0) * K + ks];
            acc[c] = __builtin_amdgcn_mfma_f32_16x16x32_bf16(ah, bh, acc[c], 0, 0, 0);
            acc[c] = __builtin_amdgcn_mfma_f32_16x16x32_bf16(ah, bl, acc[c], 0, 0, 0);
            acc[c] = __builtin_amdgcn_mfma_f32_16x16x32_bf16(al, bh, acc[c], 0, 0, 0);
        }
    }
    const int orow = blockIdx.x * 64 + w * 16 + kq * 4;  // C/D: col=lane&15, row=(lane>>4)*4+reg
#pragma unroll
    for (int rg = 0; rg < 4; ++rg) {
        int gr = orow + rg;
        if (gr < n) {
            float di = rsqrtf((float)(cnt[gr] + 1));
#pragma unroll
            for (int c = 0; c < 4; ++c)
                G[(size_t)gr * 64 + c * 16 + r0] = f2bf(acc[c][rg] * di);
        }
    }
}

// --- G[n,64] = bf16( (A[n,64] @ W[64,64]) * rsqrt(cnt+1) ), A = bf16 exact --
__global__ __launch_bounds__(256) void k_mm_bf16A(const unsigned short* __restrict__ A,
                                                  const short* __restrict__ Wth,
                                                  const short* __restrict__ Wtl,
                                                  const int* __restrict__ cnt,
                                                  unsigned short* __restrict__ G, int n) {
    constexpr int K = 64;
    const int lane = threadIdx.x & 63;
    const int w = threadIdx.x >> 6;
    const int r0 = lane & 15;
    const int kq = lane >> 4;
    const int arow = blockIdx.x * 64 + w * 16 + r0;
    const unsigned short* ar = A + (size_t)(arow < n ? arow : n - 1) * K;

    f32x4 acc[4] = {};
#pragma unroll
    for (int kc = 0; kc < K / 32; ++kc) {
        const int ks = kc * 32 + kq * 8;
        bf16x8 a = __builtin_nontemporal_load((const bf16x8*)&ar[ks]);
#pragma unroll
        for (int c = 0; c < 4; ++c) {
            bf16x8 bh = *(const bf16x8*)&Wth[(c * 16 + r0) * K + ks];
            bf16x8 bl = *(const bf16x8*)&Wtl[(c * 16 + r0) * K + ks];
            acc[c] = __builtin_amdgcn_mfma_f32_16x16x32_bf16(a, bh, acc[c], 0, 0, 0);
            acc[c] = __builtin_amdgcn_mfma_f32_16x16x32_bf16(a, bl, acc[c], 0, 0, 0);
        }
    }
    const int orow = blockIdx.x * 64 + w * 16 + kq * 4;
#pragma unroll
    for (int rg = 0; rg < 4; ++rg) {
        int gr = orow + rg;
        if (gr < n) {
            float di = rsqrtf((float)(cnt[gr] + 1));
#pragma unroll
            for (int c = 0; c < 4; ++c)
                G[(size_t)gr * 64 + c * 16 + r0] = f2bf(acc[c][rg] * di);
        }
    }
}

// --- ELL gather, 8 edges in flight; g pre-scaled --------------------------
// out[i] = act( dinv[i]*( g[i] + Σ_p g[s_p] ) + b ),  dinv = rsqrt(cnt+1)
template <bool RELU, bool OUTBF>
__global__ __launch_bounds__(256) void k_gather8(const unsigned short* __restrict__ g,
                                                 const int* __restrict__ cntArr,
                                                 const int* __restrict__ col_ell,
                                                 const float* __restrict__ bias,
                                                 void* __restrict__ dest, int n) {
    const int node = blockIdx.x * 4 + (threadIdx.x >> 6);
    if (node >= n) return;
    const int lane = threadIdx.x & 63;
    const int grp = lane >> 3;   // 0..7 : edge sub-group
    const int fl = lane & 7;     // feature octet [fl*8, fl*8+8)
    const int cn = cntArr[node];
    const int lc = min(cn, MD);
    const float dn = rsqrtf((float)(cn + 1));
    const int myidx = col_ell[(size_t)node * MD + lane];  // lane>=lc: stale, shfl-gated

    float acc[8] = {};
    if (grp == 0) {  // self loop (g already carries dinv[node] once)
        u32x4 u = *(const u32x4*)&g[(size_t)node * 64 + fl * 8];
#pragma unroll
        for (int k = 0; k < 4; ++k) {
            acc[2 * k]     = bf2f((unsigned short)(u[k] & 0xFFFF));
            acc[2 * k + 1] = bf2f((unsigned short)(u[k] >> 16));
        }
    }
    for (int j8 = 0; j8 < lc; j8 += 8) {
        int j = j8 + grp;
        int s = __shfl(myidx, j);
        if (j < lc) {
            u32x4 u = *(const u32x4*)&g[(size_t)s * 64 + fl * 8];
#pragma unroll
            for (int k = 0; k < 4; ++k) {
                acc[2 * k]     += bf2f((unsigned short)(u[k] & 0xFFFF));
                acc[2 * k + 1] += bf2f((unsigned short)(u[k] >> 16));
            }
        }
    }
#pragma unroll
    for (int k = 0; k < 8; ++k) {
        acc[k] += __shfl_xor(acc[k], 8);
        acc[k] += __shfl_xor(acc[k], 16);
        acc[k] += __shfl_xor(acc[k], 32);
    }
    if (grp == 0) {
        float v[8];
        const float* bv = &bias[fl * 8];
#pragma unroll
        for (int k = 0; k < 8; ++k) {
            v[k] = fmaf(acc[k], dn, bv[k]);
            if (RELU) v[k] = fmaxf(v[k], 0.f);
        }
        if (OUTBF) {
            u32x4 o;
            o[0] = (unsigned)f2bf(v[0]) | ((unsigned)f2bf(v[1]) << 16);
            o[1] = (unsigned)f2bf(v[2]) | ((unsigned)f2bf(v[3]) << 16);
            o[2] = (unsigned)f2bf(v[4]) | ((unsigned)f2bf(v[5]) << 16);
            o[3] = (unsigned)f2bf(v[6]) | ((unsigned)f2bf(v[7]) << 16);
            *(u32x4*)&((unsigned short*)dest)[(size_t)node * 64 + fl * 8] = o;
        } else {
            float* dp = &((float*)dest)[(size_t)node * 64 + fl * 8];
            __builtin_nontemporal_store(*(const f32x4*)&v[0], (f32x4*)&dp[0]);
            __builtin_nontemporal_store(*(const f32x4*)&v[4], (f32x4*)&dp[4]);
        }
    }
}

extern "C" void kernel_launch(void* const* d_in, const int* in_sizes, int n_in,
                              void* d_out, int out_size, void* d_ws, size_t ws_size,
                              hipStream_t stream) {
    const float* x  = (const float*)d_in[0];
    const int*   ei = (const int*)d_in[1];
    const float* W1 = (const float*)d_in[2];
    const float* b1 = (const float*)d_in[3];
    const float* W2 = (const float*)d_in[4];
    const float* b2 = (const float*)d_in[5];

    const int N = in_sizes[0] / 128;   // 100000
    const int E = in_sizes[1] / 2;     // 1000000
    const int* src = ei;
    const int* dst = ei + E;
    float* out = (float*)d_out;

    // ws layout (64B-aligned slices)
    char* ws = (char*)d_ws;
    size_t off = 0;
    auto alloc = [&](size_t bytes) {
        void* p = ws + off;
        off += (bytes + 63) & ~(size_t)63;
        return p;
    };
    unsigned short* a1   = (unsigned short*)alloc((size_t)N * 64 * 2);  // bf16 act
    unsigned short* gbuf = (unsigned short*)alloc((size_t)N * 64 * 2);  // bf16 g
    int*   cnt     = (int*)alloc((size_t)N * 4);
    int*   col_ell = (int*)alloc(((size_t)N * MD + 64) * 4);  // +64 pad (64-lane row read)
    short* W1th    = (short*)alloc((size_t)64 * 128 * 2);
    short* W1tl    = (short*)alloc((size_t)64 * 128 * 2);
    short* W2th    = (short*)alloc((size_t)64 * 64 * 2);
    short* W2tl    = (short*)alloc((size_t)64 * 64 * 2);

    const int NBZ   = (N + 255) / 256;
    const int NB_MM = (N + 63) / 64;
    const int NB_G  = (N + 3) / 4;
    const int npx   = (N + 7) / 8;     // nodes per XCD partition

    // prep: zero cnt + convert both weights (one dispatch)
    k_prep<<<NBZ + 192, 256, 0, stream>>>(cnt, N, NBZ, W1, W1th, W1tl, W2, W2th, W2tl);

    // XCD-partitioned ELL fill (full machine, standalone — fusion hurts)
    k_fill_xcd<<<8192, 256, 0, stream>>>(src, dst, E, cnt, col_ell, npx);

    // ---- layer 1 ----
    k_mm_f32A<128><<<NB_MM, 256, 0, stream>>>(x, W1th, W1tl, cnt, gbuf, N);
    k_gather8<true, true><<<NB_G, 256, 0, stream>>>(gbuf, cnt, col_ell, b1, a1, N);

    // ---- layer 2 ----
    k_mm_bf16A<<<NB_MM, 256, 0, stream>>>(a1, W2th, W2tl, cnt, gbuf, N);
    k_gather8<false, false><<<NB_G, 256, 0, stream>>>(gbuf, cnt, col_ell, b2, out, N);
}